// Round 1
// baseline (1712.047 us; speedup 1.0000x reference)
//
#include <hip/hip_runtime.h>
#include <hip/hip_bf16.h>

// Problem sizes (fixed by reference)
#define B_ 128
#define P_ 2048
#define F_ 512
#define H_ 256
#define C_ 16

typedef __attribute__((ext_vector_type(8))) __bf16 bf16x8;
typedef __attribute__((ext_vector_type(4))) float f32x4;

__device__ __forceinline__ unsigned short f2bf(float f) {
  union { float f; unsigned u; } x; x.f = f;
  unsigned r = x.u + 0x7fffu + ((x.u >> 16) & 1u);   // RNE
  return (unsigned short)(r >> 16);
}
__device__ __forceinline__ float bf2f(unsigned short u) {
  union { unsigned u; float f; } x; x.u = ((unsigned)u) << 16;
  return x.f;
}

typedef __attribute__((address_space(1))) void as1_void;
typedef __attribute__((address_space(3))) void as3_void;
__device__ __forceinline__ void gload_lds16(const void* g, void* l) {
  // async global->LDS, 16B per lane; LDS dest = wave-uniform base + lane*16
  __builtin_amdgcn_global_load_lds((as1_void*)g, (as3_void*)l, 16, 0, 0);
}

// ---------------------------------------------------------------------------
// NT GEMM: C[m,n] = sum_k A[m,k] * Bt[n,k]   (A:[M,K], Bt:[N,K], C:[M,N], all
// row-major, ldA=ldB=K, ldC=N). bf16 inputs (or fp32 Bt converted in staging),
// fp32 MFMA accumulate. 128x128 tile, BK=64, 4 waves (each 64x64 = 4x4 frags
// of 16x16x32). EPI: 0 = raw bf16 store, 1 = tanh(x + bias[col]) bf16 store.
// ---------------------------------------------------------------------------
template<int EPI, bool BF32>
__global__ __launch_bounds__(256) void gemm_nt(
    const unsigned short* __restrict__ A, long aStr,
    const void* __restrict__ Bt_, long bStr,
    unsigned short* __restrict__ C, long cStr,
    const float* __restrict__ bias,
    int M, int N, int K)
{
  __shared__ unsigned short As[128 * 64];   // [m][k]
  __shared__ unsigned short Bs[128 * 64];   // [n][k]

  const int zb = blockIdx.z;
  const unsigned short* Ab = A + (long)zb * aStr;
  unsigned short* Cb = C + (long)zb * cStr;
  const unsigned short* Btb = nullptr;
  const float* Btf = nullptr;
  if constexpr (BF32) Btf = (const float*)Bt_ + (long)zb * bStr;
  else                Btb = (const unsigned short*)Bt_ + (long)zb * bStr;

  const int tid  = threadIdx.x;
  const int lane = tid & 63;
  const int wave = tid >> 6;
  const int wr = wave >> 1, wc = wave & 1;      // 2x2 wave grid
  const int l16 = lane & 15, lhi = lane >> 4;   // MFMA lane decomposition
  const int m0 = blockIdx.y * 128, n0 = blockIdx.x * 128;

  f32x4 acc[4][4] = {};

  for (int k0 = 0; k0 < K; k0 += 64) {
    // ---- stage A tile (128x64 bf16 = 16KB) via async global->LDS ----
#pragma unroll
    for (int i = 0; i < 4; ++i) {
      int e = i * 2048 + tid * 8;               // elem offset in As
      gload_lds16(Ab + (long)(m0 + (e >> 6)) * K + k0 + (e & 63), As + e);
    }
    // ---- stage Bt tile ----
    if constexpr (!BF32) {
#pragma unroll
      for (int i = 0; i < 4; ++i) {
        int e = i * 2048 + tid * 8;
        gload_lds16(Btb + (long)(n0 + (e >> 6)) * K + k0 + (e & 63), Bs + e);
      }
    } else {
      // fp32 source: reg-stage + convert (RNE) + ds_write_b64
#pragma unroll
      for (int i = 0; i < 8; ++i) {
        int e = i * 1024 + tid * 4;
        float4 v = *(const float4*)(Btf + (long)(n0 + (e >> 6)) * K + k0 + (e & 63));
        ushort4 o; o.x = f2bf(v.x); o.y = f2bf(v.y); o.z = f2bf(v.z); o.w = f2bf(v.w);
        *(ushort4*)(Bs + e) = o;
      }
    }
    __syncthreads();  // drains vmcnt (global_load_lds) + lgkmcnt

    // ---- MFMA inner loop ----
#pragma unroll
    for (int kk = 0; kk < 64; kk += 32) {
      bf16x8 af[4], bfr[4];
#pragma unroll
      for (int m = 0; m < 4; ++m)
        af[m] = *(const bf16x8*)&As[(wr * 64 + m * 16 + l16) * 64 + kk + lhi * 8];
#pragma unroll
      for (int n = 0; n < 4; ++n)
        bfr[n] = *(const bf16x8*)&Bs[(wc * 64 + n * 16 + l16) * 64 + kk + lhi * 8];
#pragma unroll
      for (int m = 0; m < 4; ++m)
#pragma unroll
        for (int n = 0; n < 4; ++n)
          acc[m][n] = __builtin_amdgcn_mfma_f32_16x16x32_bf16(af[m], bfr[n], acc[m][n], 0, 0, 0);
    }
    __syncthreads();
  }

  // ---- epilogue: C/D layout col=lane&15, row=(lane>>4)*4+j (m89/m91) ----
#pragma unroll
  for (int m = 0; m < 4; ++m) {
#pragma unroll
    for (int n = 0; n < 4; ++n) {
      int col = n0 + wc * 64 + n * 16 + l16;
      float bv = 0.f;
      if constexpr (EPI == 1) bv = bias[col];
#pragma unroll
      for (int j = 0; j < 4; ++j) {
        int row = m0 + wr * 64 + m * 16 + lhi * 4 + j;
        float v = acc[m][n][j];
        if constexpr (EPI == 1) v = tanhf(v + bv);
        Cb[(long)row * N + col] = f2bf(v);
      }
    }
  }
}

// ---------------------------------------------------------------------------
// Small helpers
// ---------------------------------------------------------------------------
__global__ __launch_bounds__(256) void cvt_bf16(const float* __restrict__ in,
                                                unsigned short* __restrict__ out, int n4) {
  int i = blockIdx.x * 256 + threadIdx.x;
  if (i >= n4) return;
  float4 v = ((const float4*)in)[i];
  ushort4 o; o.x = f2bf(v.x); o.y = f2bf(v.y); o.z = f2bf(v.z); o.w = f2bf(v.w);
  ((ushort4*)out)[i] = o;
}

// out[c*R + r] = bf16(in[r*Cc + c])  (transpose + convert; tiny weights only)
__global__ __launch_bounds__(256) void tcvt_bf16(const float* __restrict__ in,
                                                 unsigned short* __restrict__ out, int R, int Cc) {
  int idx = blockIdx.x * 256 + threadIdx.x;
  if (idx >= R * Cc) return;
  int r = idx / Cc, c = idx - r * Cc;
  out[c * R + r] = f2bf(in[idx]);
}

// s[row] = tanh(dot(h2[row,:], lw1) + lb1); one wave per row, 4 rows/block
__global__ __launch_bounds__(256) void rowdot_tanh(const unsigned short* __restrict__ h2,
    const float* __restrict__ lw1, const float* __restrict__ lb1, float* __restrict__ s) {
  int row  = blockIdx.x * 4 + (threadIdx.x >> 6);
  int lane = threadIdx.x & 63;
  ushort4 v = ((const ushort4*)(h2 + (long)row * H_))[lane];
  float4  w = ((const float4*)lw1)[lane];
  float sum = bf2f(v.x) * w.x + bf2f(v.y) * w.y + bf2f(v.z) * w.z + bf2f(v.w) * w.w;
#pragma unroll
  for (int off = 32; off > 0; off >>= 1) sum += __shfl_xor(sum, off, 64);
  if (lane == 0) s[row] = tanhf(sum + lb1[0]);
}

// out[b] = sum_p s[b,p]*lw2[p] + sum_c clin[b,c]*lw2[P+c] + lb2
__global__ __launch_bounds__(256) void final_dot(const float* __restrict__ s,
    const float* __restrict__ clin, const float* __restrict__ lw2,
    const float* __restrict__ lb2, float* __restrict__ out) {
  int b = blockIdx.x, t = threadIdx.x;
  float sum = 0.f;
#pragma unroll
  for (int i = 0; i < P_ / 256; ++i) { int p = i * 256 + t; sum += s[b * P_ + p] * lw2[p]; }
  if (t < C_) sum += clin[b * C_ + t] * lw2[P_ + t];
#pragma unroll
  for (int off = 32; off > 0; off >>= 1) sum += __shfl_xor(sum, off, 64);
  __shared__ float red[4];
  if ((t & 63) == 0) red[t >> 6] = sum;
  __syncthreads();
  if (t == 0) out[b] = red[0] + red[1] + red[2] + red[3] + lb2[0];
}

// ---------------------------------------------------------------------------
extern "C" void kernel_launch(void* const* d_in, const int* in_sizes, int n_in,
                              void* d_out, int out_size, void* d_ws, size_t ws_size,
                              hipStream_t stream) {
  const float* x    = (const float*)d_in[0];
  const float* adj  = (const float*)d_in[1];
  const float* clin = (const float*)d_in[2];
  const float* W1   = (const float*)d_in[3];
  const float* b1   = (const float*)d_in[4];
  const float* W2   = (const float*)d_in[5];
  const float* b2   = (const float*)d_in[6];
  const float* lw1  = (const float*)d_in[7];
  const float* lb1  = (const float*)d_in[8];
  const float* lw2  = (const float*)d_in[9];
  const float* lb2  = (const float*)d_in[10];
  float* out = (float*)d_out;

  // workspace carve (278.3 MB total)
  char* w = (char*)d_ws;
  unsigned short* adjb = (unsigned short*)(w);                   // P*P bf16   (8 MiB)
  unsigned short* W1t  = (unsigned short*)(w + 8388608);         // [H,F] bf16
  unsigned short* W2t  = (unsigned short*)(w + 8650752);         // [H,H] bf16
  float*          sbuf = (float*)(w + 8781824);                  // [B,P] f32
  unsigned short* bufA = (unsigned short*)(w + 9830400);         // 134 MB ping
  unsigned short* bufB = (unsigned short*)(w + 144048128);       // 134 MB pong

  // weight / adjacency conversion
  hipLaunchKernelGGL(cvt_bf16, dim3(P_ * P_ / 4 / 256), dim3(256), 0, stream,
                     adj, adjb, P_ * P_ / 4);
  hipLaunchKernelGGL(tcvt_bf16, dim3((F_ * H_ + 255) / 256), dim3(256), 0, stream,
                     W1, W1t, F_, H_);
  hipLaunchKernelGGL(tcvt_bf16, dim3((H_ * H_ + 255) / 256), dim3(256), 0, stream,
                     W2, W2t, H_, H_);

  // K1: S1T_b[h,p] = sum_f W1t[h,f] * x_b[p,f]      (M=H, N=P, K=F; Bt fp32)
  hipLaunchKernelGGL((gemm_nt<0, true>), dim3(P_ / 128, H_ / 128, B_), dim3(256), 0, stream,
      W1t, 0L, (const void*)x, (long)P_ * F_, bufA, (long)H_ * P_,
      (const float*)nullptr, H_, P_, F_);

  // K2: h1_b[p,h] = tanh(sum_q adj[p,q] * S1T_b[h,q] + b1[h])   (M=P, N=H, K=P)
  hipLaunchKernelGGL((gemm_nt<1, false>), dim3(H_ / 128, P_ / 128, B_), dim3(256), 0, stream,
      adjb, 0L, (const void*)bufA, (long)H_ * P_, bufB, (long)P_ * H_,
      b1, P_, H_, P_);

  // K3: S2T_b[h,p] = sum_h' W2t[h,h'] * h1_b[p,h']  (M=H, N=P, K=H)
  hipLaunchKernelGGL((gemm_nt<0, false>), dim3(P_ / 128, H_ / 128, B_), dim3(256), 0, stream,
      W2t, 0L, (const void*)bufB, (long)P_ * H_, bufA, (long)H_ * P_,
      (const float*)nullptr, H_, P_, H_);

  // K4: h2_b[p,h] = tanh(sum_q adj[p,q] * S2T_b[h,q] + b2[h])
  hipLaunchKernelGGL((gemm_nt<1, false>), dim3(H_ / 128, P_ / 128, B_), dim3(256), 0, stream,
      adjb, 0L, (const void*)bufA, (long)H_ * P_, bufB, (long)P_ * H_,
      b2, P_, H_, P_);

  // s = tanh(h2 . lw1 + lb1)
  hipLaunchKernelGGL(rowdot_tanh, dim3(B_ * P_ / 4), dim3(256), 0, stream,
                     bufB, lw1, lb1, sbuf);

  // out[b]
  hipLaunchKernelGGL(final_dot, dim3(B_), dim3(256), 0, stream,
                     sbuf, clin, lw2, lb2, out);
}

// Round 2
// 1437.388 us; speedup vs baseline: 1.1911x; 1.1911x over previous
//
#include <hip/hip_runtime.h>
#include <hip/hip_bf16.h>

// Problem sizes (fixed by reference)
#define B_ 128
#define P_ 2048
#define F_ 512
#define H_ 256
#define C_ 16

typedef __attribute__((ext_vector_type(8))) __bf16 bf16x8;
typedef __attribute__((ext_vector_type(4))) float f32x4;

__device__ __forceinline__ unsigned short f2bf(float f) {
  union { float f; unsigned u; } x; x.f = f;
  unsigned r = x.u + 0x7fffu + ((x.u >> 16) & 1u);   // RNE
  return (unsigned short)(r >> 16);
}
__device__ __forceinline__ float bf2f(unsigned short u) {
  union { unsigned u; float f; } x; x.u = ((unsigned)u) << 16;
  return x.f;
}

typedef __attribute__((address_space(1))) void as1_void;
typedef __attribute__((address_space(3))) void as3_void;
__device__ __forceinline__ void gload_lds16(const void* g, void* l) {
  __builtin_amdgcn_global_load_lds((as1_void*)g, (as3_void*)l, 16, 0, 0);
}

// ===========================================================================
// 8-phase 256x256 NT GEMM (bf16), 8 waves (2M x 4N), BK=64, dbuf LDS 128KB.
// C[m,n] = tanh( sum_k A[m,k]*Bt[n,k] + bias[n & 255] ), bf16 out.
// LDS layout per K-tile buffer: A[256][64] + B[256][64], 16B-chunk XOR swizzle
// chunk(r,j) holds source chunk j ^ (r&7); staging pre-swizzles the GLOBAL
// source address so global_load_lds writes linearly (both-sides rule, m231).
// Phase order per K-tile: Q(0,0) Q(1,0) Q(1,1) Q(0,1) so each LDS half
// retires exactly one phase before its re-stage. vmcnt(4) once per K-tile.
// ===========================================================================
__global__ __launch_bounds__(512, 2) void gemm256(
    const unsigned short* __restrict__ A,
    const unsigned short* __restrict__ Bt,
    unsigned short* __restrict__ C,
    const float* __restrict__ bias,
    int M, int N, int K)
{
  __shared__ unsigned short lds[65536];   // 128 KiB

  const int tid  = threadIdx.x;
  const int lane = tid & 63;
  const int wv   = tid >> 6;             // 0..7
  const int wr   = wv >> 2, wc = wv & 3; // 2x4 wave grid, wave tile 128x64
  const int l16  = lane & 15, lhi = lane >> 4;
  const int NT   = K >> 6;

  // XCD-aware swizzle (nwg % 8 == 0 here); m fastest within an XCD chunk so
  // each Bt 256-row panel (1MB) is reused by 8 consecutive m-blocks from L2.
  {
  }
  const int nwg = gridDim.x, cpx = nwg >> 3;
  const int swz = (blockIdx.x & 7) * cpx + (blockIdx.x >> 3);
  const int ntm = M >> 8;
  const int m0 = (swz % ntm) * 256;
  const int n0 = (swz / ntm) * 256;

  f32x4 acc[2][2][4][2] = {};   // [mh][nh][mf][nf]

  // stage one 128-row half-tile (2 global_load_lds lines of 8KB each).
  // op: 0=A, 1=B. Buffer parity from t; source tile clamped (dummy re-stage
  // of the last tile into dead buffer halves keeps vmcnt counting uniform).
  auto stage = [&](int op, int half, int t) {
    const int ts = t < NT ? t : NT - 1;
    const unsigned short* src = op ? Bt : A;
    const int row0 = (op ? n0 : m0) + half * 128;
    unsigned short* ldst = lds + ((t & 1) << 15) + (op << 14) + (half << 13) + tid * 8;
    const int rsub = tid >> 3;
    const int k16  = (tid & 7) ^ (rsub & 7);               // pre-swizzled source chunk
    const long kk  = (long)ts * 64 + k16 * 8;
    gload_lds16(src + (long)(row0 + rsub) * K + kk, ldst);
    gload_lds16(src + (long)(row0 + 64 + rsub) * K + kk, ldst + 4096);
  };

  // ---- prologue: tile0 fully + tile1 {Bh0, Ah1}; 12 lines/wave ----
  stage(0, 0, 0); stage(0, 1, 0); stage(1, 0, 0); stage(1, 1, 0);
  stage(1, 0, 1); stage(0, 1, 1);
  asm volatile("s_waitcnt vmcnt(4)" ::: "memory");   // tile0 complete
  __builtin_amdgcn_s_barrier();

#pragma unroll 1
  for (int t = 0; t < NT; ++t) {
    bf16x8 a[2][4], b[2][2];
    const int bufo = (t & 1) << 15;

    auto loadA = [&](int mh) {
#pragma unroll
      for (int ks = 0; ks < 2; ++ks)
#pragma unroll
        for (int mf = 0; mf < 4; ++mf) {
          int r = wr * 128 + mh * 64 + mf * 16 + l16;
          int k16 = ks * 4 + lhi;
          a[ks][mf] = *(const bf16x8*)&lds[bufo + (r << 6) + ((k16 ^ (r & 7)) << 3)];
        }
    };
    auto loadB = [&](int nh) {
#pragma unroll
      for (int ks = 0; ks < 2; ++ks)
#pragma unroll
        for (int nf = 0; nf < 2; ++nf) {
          int r = wc * 64 + nh * 32 + nf * 16 + l16;
          int k16 = ks * 4 + lhi;
          b[ks][nf] = *(const bf16x8*)&lds[bufo + 16384 + (r << 6) + ((k16 ^ (r & 7)) << 3)];
        }
    };
    auto domfma = [&](int mh, int nh) {
      __builtin_amdgcn_s_setprio(1);
#pragma unroll
      for (int ks = 0; ks < 2; ++ks)
#pragma unroll
        for (int mf = 0; mf < 4; ++mf)
#pragma unroll
          for (int nf = 0; nf < 2; ++nf)
            acc[mh][nh][mf][nf] = __builtin_amdgcn_mfma_f32_16x16x32_bf16(
                a[ks][mf], b[ks][nf], acc[mh][nh][mf][nf], 0, 0, 0);
      __builtin_amdgcn_s_setprio(0);
    };

#define MIDSYNC  __builtin_amdgcn_s_barrier(); \
                 asm volatile("s_waitcnt lgkmcnt(0)" ::: "memory"); \
                 __builtin_amdgcn_sched_barrier(0);
#define ENDSYNC  __builtin_amdgcn_s_barrier(); \
                 asm volatile("" ::: "memory");

    // phase 0: Q(0,0); stage (t+1, A h0)
    loadA(0); loadB(0);
    stage(0, 0, t + 1);
    MIDSYNC; domfma(0, 0); ENDSYNC;

    // phase 1: Q(1,0) — new A(h1), reuse b; stage (t+1, B h1)
    loadA(1);
    stage(1, 1, t + 1);
    MIDSYNC; domfma(1, 0); ENDSYNC;

    // phase 2: Q(1,1) — reuse a, new B(h1); stage (t+2, B h0)
    loadB(1);
    stage(1, 0, t + 2);
    MIDSYNC; domfma(1, 1); ENDSYNC;

    // phase 3: Q(0,1) — new A(h0), reuse b; stage (t+2, A h1); counted vmcnt
    loadA(0);
    stage(0, 1, t + 2);
    asm volatile("s_waitcnt vmcnt(4)" ::: "memory");   // tile t+1 fully landed
    MIDSYNC; domfma(0, 1); ENDSYNC;
  }
#undef MIDSYNC
#undef ENDSYNC

  // epilogue: C/D layout col=lane&15, row=(lane>>4)*4+j
#pragma unroll
  for (int mh = 0; mh < 2; ++mh)
#pragma unroll
    for (int nh = 0; nh < 2; ++nh)
#pragma unroll
      for (int mf = 0; mf < 4; ++mf)
#pragma unroll
        for (int nf = 0; nf < 2; ++nf) {
          int col = n0 + wc * 64 + nh * 32 + nf * 16 + l16;
          float bv = bias[col & (H_ - 1)];
#pragma unroll
          for (int j = 0; j < 4; ++j) {
            int row = m0 + wr * 128 + mh * 64 + mf * 16 + lhi * 4 + j;
            C[(long)row * N + col] = f2bf(tanhf(acc[mh][nh][mf][nf][j] + bv));
          }
        }
}

// ===========================================================================
// 128x128 2-barrier NT GEMM (kept for K1 fp32-B and batched K3), ld-general.
// ===========================================================================
template<int EPI, bool BF32>
__global__ __launch_bounds__(256) void gemm_nt(
    const unsigned short* __restrict__ A, long aStr, int ldA,
    const void* __restrict__ Bt_, long bStr, int ldB,
    unsigned short* __restrict__ C, long cStr, int ldC,
    const float* __restrict__ bias,
    int M, int N, int K)
{
  __shared__ unsigned short As[128 * 64];
  __shared__ unsigned short Bs[128 * 64];

  const int zb = blockIdx.z;
  const unsigned short* Ab = A + (long)zb * aStr;
  unsigned short* Cb = C + (long)zb * cStr;
  const unsigned short* Btb = nullptr;
  const float* Btf = nullptr;
  if constexpr (BF32) Btf = (const float*)Bt_ + (long)zb * bStr;
  else                Btb = (const unsigned short*)Bt_ + (long)zb * bStr;

  const int tid  = threadIdx.x;
  const int lane = tid & 63;
  const int wave = tid >> 6;
  const int wr = wave >> 1, wc = wave & 1;
  const int l16 = lane & 15, lhi = lane >> 4;
  const int m0 = blockIdx.y * 128, n0 = blockIdx.x * 128;

  f32x4 acc[4][4] = {};

  for (int k0 = 0; k0 < K; k0 += 64) {
#pragma unroll
    for (int i = 0; i < 4; ++i) {
      int e = i * 2048 + tid * 8;
      gload_lds16(Ab + (long)(m0 + (e >> 6)) * ldA + k0 + (e & 63), As + e);
    }
    if constexpr (!BF32) {
#pragma unroll
      for (int i = 0; i < 4; ++i) {
        int e = i * 2048 + tid * 8;
        gload_lds16(Btb + (long)(n0 + (e >> 6)) * ldB + k0 + (e & 63), Bs + e);
      }
    } else {
#pragma unroll
      for (int i = 0; i < 8; ++i) {
        int e = i * 1024 + tid * 4;
        float4 v = *(const float4*)(Btf + (long)(n0 + (e >> 6)) * ldB + k0 + (e & 63));
        ushort4 o; o.x = f2bf(v.x); o.y = f2bf(v.y); o.z = f2bf(v.z); o.w = f2bf(v.w);
        *(ushort4*)(Bs + e) = o;
      }
    }
    __syncthreads();

#pragma unroll
    for (int kk = 0; kk < 64; kk += 32) {
      bf16x8 af[4], bfr[4];
#pragma unroll
      for (int m = 0; m < 4; ++m)
        af[m] = *(const bf16x8*)&As[(wr * 64 + m * 16 + l16) * 64 + kk + lhi * 8];
#pragma unroll
      for (int n = 0; n < 4; ++n)
        bfr[n] = *(const bf16x8*)&Bs[(wc * 64 + n * 16 + l16) * 64 + kk + lhi * 8];
#pragma unroll
      for (int m = 0; m < 4; ++m)
#pragma unroll
        for (int n = 0; n < 4; ++n)
          acc[m][n] = __builtin_amdgcn_mfma_f32_16x16x32_bf16(af[m], bfr[n], acc[m][n], 0, 0, 0);
    }
    __syncthreads();
  }

#pragma unroll
  for (int m = 0; m < 4; ++m) {
#pragma unroll
    for (int n = 0; n < 4; ++n) {
      int col = n0 + wc * 64 + n * 16 + l16;
      float bv = 0.f;
      if constexpr (EPI == 1) bv = bias[col & (H_ - 1)];
#pragma unroll
      for (int j = 0; j < 4; ++j) {
        int row = m0 + wr * 64 + m * 16 + lhi * 4 + j;
        float v = acc[m][n][j];
        if constexpr (EPI == 1) v = tanhf(v + bv);
        Cb[(long)row * ldC + col] = f2bf(v);
      }
    }
  }
}

// ---------------------------------------------------------------------------
__global__ __launch_bounds__(256) void cvt_bf16(const float* __restrict__ in,
                                                unsigned short* __restrict__ out, int n4) {
  int i = blockIdx.x * 256 + threadIdx.x;
  if (i >= n4) return;
  float4 v = ((const float4*)in)[i];
  ushort4 o; o.x = f2bf(v.x); o.y = f2bf(v.y); o.z = f2bf(v.z); o.w = f2bf(v.w);
  ((ushort4*)out)[i] = o;
}

__global__ __launch_bounds__(256) void tcvt_bf16(const float* __restrict__ in,
                                                 unsigned short* __restrict__ out, int R, int Cc) {
  int idx = blockIdx.x * 256 + threadIdx.x;
  if (idx >= R * Cc) return;
  int r = idx / Cc, c = idx - r * Cc;
  out[c * R + r] = f2bf(in[idx]);
}

// s[b*P + p] = tanh(dot(h2m[p, b*256:(b+1)*256], lw1) + lb1); h2m is [P][B*H]
__global__ __launch_bounds__(256) void rowdot_tanh(const unsigned short* __restrict__ h2m,
    const float* __restrict__ lw1, const float* __restrict__ lb1, float* __restrict__ s) {
  int i = blockIdx.x * 4 + (threadIdx.x >> 6);   // i = p*128 + b
  int lane = threadIdx.x & 63;
  int p = i >> 7, b = i & 127;
  ushort4 v = ((const ushort4*)(h2m + (long)p * (B_ * H_) + b * H_))[lane];
  float4  w = ((const float4*)lw1)[lane];
  float sum = bf2f(v.x) * w.x + bf2f(v.y) * w.y + bf2f(v.z) * w.z + bf2f(v.w) * w.w;
#pragma unroll
  for (int off = 32; off > 0; off >>= 1) sum += __shfl_xor(sum, off, 64);
  if (lane == 0) s[b * P_ + p] = tanhf(sum + lb1[0]);
}

__global__ __launch_bounds__(256) void final_dot(const float* __restrict__ s,
    const float* __restrict__ clin, const float* __restrict__ lw2,
    const float* __restrict__ lb2, float* __restrict__ out) {
  int b = blockIdx.x, t = threadIdx.x;
  float sum = 0.f;
#pragma unroll
  for (int i = 0; i < P_ / 256; ++i) { int p = i * 256 + t; sum += s[b * P_ + p] * lw2[p]; }
  if (t < C_) sum += clin[b * C_ + t] * lw2[P_ + t];
#pragma unroll
  for (int off = 32; off > 0; off >>= 1) sum += __shfl_xor(sum, off, 64);
  __shared__ float red[4];
  if ((t & 63) == 0) red[t >> 6] = sum;
  __syncthreads();
  if (t == 0) out[b] = red[0] + red[1] + red[2] + red[3] + lb2[0];
}

// ---------------------------------------------------------------------------
extern "C" void kernel_launch(void* const* d_in, const int* in_sizes, int n_in,
                              void* d_out, int out_size, void* d_ws, size_t ws_size,
                              hipStream_t stream) {
  const float* x    = (const float*)d_in[0];
  const float* adj  = (const float*)d_in[1];
  const float* clin = (const float*)d_in[2];
  const float* W1   = (const float*)d_in[3];
  const float* b1   = (const float*)d_in[4];
  const float* W2   = (const float*)d_in[5];
  const float* b2   = (const float*)d_in[6];
  const float* lw1  = (const float*)d_in[7];
  const float* lb1  = (const float*)d_in[8];
  const float* lw2  = (const float*)d_in[9];
  const float* lb2  = (const float*)d_in[10];
  float* out = (float*)d_out;

  char* w = (char*)d_ws;
  unsigned short* adjb = (unsigned short*)(w);                   // P*P bf16 (8 MiB)
  unsigned short* W1t  = (unsigned short*)(w + 8388608);         // [H,F] bf16
  unsigned short* W2t  = (unsigned short*)(w + 8650752);         // [H,H] bf16
  float*          sbuf = (float*)(w + 8781824);                  // [B,P] f32
  unsigned short* bufA = (unsigned short*)(w + 9830400);         // 134 MB: [(b,h), p]
  unsigned short* bufB = (unsigned short*)(w + 144048128);       // 134 MB: [p, (b,h)]

  hipLaunchKernelGGL(cvt_bf16, dim3(P_ * P_ / 4 / 256), dim3(256), 0, stream,
                     adj, adjb, P_ * P_ / 4);
  hipLaunchKernelGGL(tcvt_bf16, dim3((F_ * H_ + 255) / 256), dim3(256), 0, stream,
                     W1, W1t, F_, H_);
  hipLaunchKernelGGL(tcvt_bf16, dim3((H_ * H_ + 255) / 256), dim3(256), 0, stream,
                     W2, W2t, H_, H_);

  // K1: bufA[(b,h), p] = sum_f W1t[h,f] * x[b,p,f]   (batched, Bt=fp32 x)
  hipLaunchKernelGGL((gemm_nt<0, true>), dim3(P_ / 128, H_ / 128, B_), dim3(256), 0, stream,
      W1t, 0L, F_, (const void*)x, (long)P_ * F_, F_, bufA, (long)H_ * P_, P_,
      (const float*)nullptr, H_, P_, F_);

  // K2 (merged over batch): bufB[p, (b,h)] = tanh(adj @ bufA^T + b1)
  hipLaunchKernelGGL(gemm256, dim3((P_ / 256) * (B_ * H_ / 256)), dim3(512), 0, stream,
      adjb, bufA, bufB, b1, P_, B_ * H_, P_);

  // K3: bufA[(b,h), p] = sum_h' W2t[h,h'] * bufB[p, b*256+h']   (batched)
  hipLaunchKernelGGL((gemm_nt<0, false>), dim3(P_ / 128, H_ / 128, B_), dim3(256), 0, stream,
      W2t, 0L, H_, (const void*)bufB, 256L, B_ * H_, bufA, (long)H_ * P_, P_,
      (const float*)nullptr, H_, P_, H_);

  // K4 (merged): bufB[p, (b,h)] = tanh(adj @ bufA^T + b2)
  hipLaunchKernelGGL(gemm256, dim3((P_ / 256) * (B_ * H_ / 256)), dim3(512), 0, stream,
      adjb, bufA, bufB, b2, P_, B_ * H_, P_);

  // s = tanh(h2 . lw1 + lb1)
  hipLaunchKernelGGL(rowdot_tanh, dim3(B_ * P_ / 4), dim3(256), 0, stream,
                     bufB, lw1, lb1, sbuf);

  hipLaunchKernelGGL(final_dot, dim3(B_), dim3(256), 0, stream,
                     sbuf, clin, lw2, lb2, out);
}